// Round 1
// baseline (5042.104 us; speedup 1.0000x reference)
//
#include <hip/hip_runtime.h>

#define NN 60000
#define EE 600000
#define BB 1024
#define LL 3

// ---------------- CSR construction ----------------

__global__ __launch_bounds__(256) void count_k(const int* __restrict__ dst,
                                               int* __restrict__ counts, int E_) {
  int e = blockIdx.x * 256 + threadIdx.x;
  if (e < E_) atomicAdd(&counts[dst[e]], 1);
}

__global__ __launch_bounds__(1024) void scan_k(const int* __restrict__ counts,
                                               int* __restrict__ rowp, int Nn) {
  __shared__ int part[1024];
  int t = threadIdx.x;
  int per = (Nn + 1023) >> 10;
  int b = t * per;
  int sum = 0;
  for (int i = 0; i < per; i++) {
    int idx = b + i;
    if (idx < Nn) sum += counts[idx];
  }
  part[t] = sum;
  for (int off = 1; off < 1024; off <<= 1) {
    __syncthreads();
    int v = (t >= off) ? part[t - off] : 0;
    __syncthreads();
    part[t] += v;
  }
  __syncthreads();
  int run = part[t] - sum;  // exclusive prefix
  for (int i = 0; i < per; i++) {
    int idx = b + i;
    if (idx < Nn) {
      rowp[idx] = run;
      run += counts[idx];
    }
  }
  if (t == 1023) rowp[Nn] = part[1023];
}

__global__ __launch_bounds__(256) void fill_k(const int* __restrict__ dst,
                                              const int* __restrict__ rowp,
                                              int* __restrict__ cursor,
                                              int* __restrict__ eidx, int E_) {
  int e = blockIdx.x * 256 + threadIdx.x;
  if (e >= E_) return;
  int d = dst[e];
  int pos = atomicAdd(&cursor[d], 1);
  eidx[rowp[d] + pos] = e;
}

// ---------------- generic fp32 GEMM: C = act(A[M,K] @ B[K,Ncol] + bias) ----------------
// K must be a multiple of 64; Ncol a multiple of 64.
// ACT: 0 = none, 1 = ELU (alpha=1), 2 = leaky_relu(0.01)

template <int ACT>
__global__ __launch_bounds__(256) void gemm_k(const float* __restrict__ A,
                                              const float* __restrict__ B,
                                              const float* __restrict__ bias,
                                              float* __restrict__ C, int M, int K,
                                              int Ncol) {
  __shared__ float As[64][65];
  __shared__ float Bs[64][65];
  int row0 = blockIdx.x * 64;
  int col0 = blockIdx.y * 64;
  int c = threadIdx.x & 63;
  int rg = threadIdx.x >> 6;  // 0..3
  float acc[16];
#pragma unroll
  for (int i = 0; i < 16; i++) acc[i] = 0.f;

  for (int k0 = 0; k0 < K; k0 += 64) {
#pragma unroll
    for (int i = 0; i < 16; i++) {
      int idx = threadIdx.x + i * 256;
      int r = idx >> 6, kk = idx & 63;
      As[r][kk] = (row0 + r < M) ? A[(size_t)(row0 + r) * K + k0 + kk] : 0.f;
    }
#pragma unroll
    for (int i = 0; i < 16; i++) {
      int idx = threadIdx.x + i * 256;
      int kk = idx >> 6, cc = idx & 63;
      Bs[kk][cc] = B[(size_t)(k0 + kk) * Ncol + col0 + cc];
    }
    __syncthreads();
#pragma unroll 16
    for (int kk = 0; kk < 64; kk++) {
      float bv = Bs[kk][c];
#pragma unroll
      for (int i = 0; i < 16; i++) acc[i] += As[rg * 16 + i][kk] * bv;
    }
    __syncthreads();
  }
#pragma unroll
  for (int i = 0; i < 16; i++) {
    int r = row0 + rg * 16 + i;
    if (r < M) {
      float v = acc[i] + (bias ? bias[col0 + c] : 0.f);
      if (ACT == 1) v = v > 0.f ? v : expm1f(v);
      if (ACT == 2) v = v > 0.f ? v : 0.01f * v;
      C[(size_t)r * Ncol + col0 + c] = v;
    }
  }
}

// ---------------- edge kernel: attention logits -> exp ----------------
// One wave (64 lanes) per edge; lane = column (h*16+fe) of H*FE=64.
// f = NI[src] + NJ[dst] + ef @ Wf + bias; leaky(0.01); logit_h = sum_fe f*attn;
// stores EX[e*4+h] = exp(logit_h).

template <int K>
__global__ __launch_bounds__(256) void edge_k(const float* __restrict__ NI,
                                              const float* __restrict__ NJ,
                                              const float* __restrict__ EF,
                                              const float* __restrict__ Wf,
                                              const float* __restrict__ attn,
                                              const float* __restrict__ bias,
                                              const int* __restrict__ src,
                                              const int* __restrict__ dst,
                                              float* __restrict__ EX, int E_) {
  __shared__ float Ws[K][64];
  __shared__ float efs[4][K];
  __shared__ float attns[64];
  __shared__ float biass[64];
  for (int idx = threadIdx.x; idx < K * 64; idx += 256) Ws[idx >> 6][idx & 63] = Wf[idx];
  if (threadIdx.x < 64) {
    attns[threadIdx.x] = attn[threadIdx.x];
    biass[threadIdx.x] = bias[threadIdx.x];
  }
  int e0 = blockIdx.x * 4;
  for (int idx = threadIdx.x; idx < 4 * K; idx += 256) {
    int le = idx / K, kk = idx % K;
    int e = e0 + le;
    efs[le][kk] = (e < E_) ? EF[(size_t)e * K + kk] : 0.f;
  }
  __syncthreads();
  int le = threadIdx.x >> 6;
  int e = e0 + le;
  if (e >= E_) return;
  int c = threadIdx.x & 63;
  int s = src[e], d = dst[e];
  float f = NI[(size_t)s * 64 + c] + NJ[(size_t)d * 64 + c] + biass[c];
#pragma unroll
  for (int k = 0; k < K; k++) f += efs[le][k] * Ws[k][c];
  f = f > 0.f ? f : 0.01f * f;
  float v = f * attns[c];
  v += __shfl_xor(v, 1);
  v += __shfl_xor(v, 2);
  v += __shfl_xor(v, 4);
  v += __shfl_xor(v, 8);
  if ((c & 15) == 0) EX[(size_t)e * 4 + (c >> 4)] = __expf(v);
}

// ---------------- per-destination-node aggregation ----------------
// 1 block = 1 node; 256 threads = (h,d) accumulator grid.
// out[n,h,d] = sum_e ex*mask*XN[src,h,d] / sum_e ex   (0 if no edges)

__global__ __launch_bounds__(256) void node_agg_k(const float* __restrict__ XN,
                                                  const float* __restrict__ EX,
                                                  const float* __restrict__ mask,
                                                  const int* __restrict__ srcArr,
                                                  const int* __restrict__ eidx,
                                                  const int* __restrict__ rowp,
                                                  float* __restrict__ HS, int Nn) {
  int n = blockIdx.x;
  int t = threadIdx.x;
  int h = t >> 6;
  int beg = rowp[n], end = rowp[n + 1];
  float acc = 0.f, ssum = 0.f;
  for (int i = beg; i < end; i++) {
    int e = eidx[i];
    float ex = EX[(size_t)e * 4 + h];
    float w = ex * mask[e];
    int s = srcArr[e];
    acc += w * XN[(size_t)s * 256 + t];
    ssum += ex;
  }
  HS[(size_t)n * 256 + t] = (ssum > 0.f) ? acc / ssum : 0.f;
}

// ---------------- gathers into head feature matrices ----------------

__global__ __launch_bounds__(64) void gather2_k(const float* __restrict__ X,
                                                const int* __restrict__ uidx,
                                                const int* __restrict__ iidx,
                                                float* __restrict__ uiX, int layer) {
  int b = blockIdx.x;
  int c = threadIdx.x;
  uiX[(size_t)b * 384 + layer * 64 + c] = X[(size_t)uidx[b] * 64 + c];
  uiX[(size_t)b * 384 + 192 + layer * 64 + c] = X[(size_t)iidx[b] * 64 + c];
}

__global__ __launch_bounds__(64) void gather1_k(const float* __restrict__ X,
                                                const int* __restrict__ sidx,
                                                float* __restrict__ sgX, int layer) {
  int b = blockIdx.x;
  int c = threadIdx.x;
  sgX[(size_t)b * 192 + layer * 64 + c] = X[(size_t)sidx[b] * 64 + c];
}

// ---------------- head MLP: sigmoid(relu(X@W1+b1)@W2+b2) ----------------
// block = 128 threads = hidden units, one batch row per block.

__global__ __launch_bounds__(128) void head_k(const float* __restrict__ Xf,
                                              const float* __restrict__ W1,
                                              const float* __restrict__ b1,
                                              const float* __restrict__ W2,
                                              const float* __restrict__ b2,
                                              float* __restrict__ out, int F) {
  __shared__ float xs[384];
  __shared__ float red[128];
  int b = blockIdx.x, t = threadIdx.x;
  for (int i = t; i < F; i += 128) xs[i] = Xf[(size_t)b * F + i];
  __syncthreads();
  float acc = b1[t];
  for (int k = 0; k < F; k++) acc += xs[k] * W1[k * 128 + t];
  acc = fmaxf(acc, 0.f);
  float v = acc * W2[t];
  v += __shfl_xor(v, 1);
  v += __shfl_xor(v, 2);
  v += __shfl_xor(v, 4);
  v += __shfl_xor(v, 8);
  v += __shfl_xor(v, 16);
  v += __shfl_xor(v, 32);
  red[t] = v;
  __syncthreads();
  if (t == 0) {
    float tot = red[0] + red[64] + b2[0];
    out[b] = 1.f / (1.f + __expf(-tot));
  }
}

// ---------------- driver ----------------

extern "C" void kernel_launch(void* const* d_in, const int* in_sizes, int n_in,
                              void* d_out, int out_size, void* d_ws, size_t ws_size,
                              hipStream_t stream) {
  const float* x_in = (const float*)d_in[0];
  const float* efeat = (const float*)d_in[1];
  const float* efeat2 = (const float*)d_in[2];
  const float* mask = (const float*)d_in[3];
  const float* mask2 = (const float*)d_in[4];
  const int* src = (const int*)d_in[5];
  const int* dst = (const int*)d_in[6];
  const int* user_idx = (const int*)d_in[7];
  const int* item_idx = (const int*)d_in[8];
  const int* subg_idx = (const int*)d_in[9];
  const float* lW_node = (const float*)d_in[10];
  const float* lW_ni = (const float*)d_in[11];
  const float* lW_nj = (const float*)d_in[12];
  const float* lW_fij = (const float*)d_in[13];
  const float* l_attn = (const float*)d_in[14];
  const float* l_bias = (const float*)d_in[15];
  const float* agg1_W = (const float*)d_in[16];
  const float* agg1_b = (const float*)d_in[17];
  const float* gW_node = (const float*)d_in[18];
  const float* gW_ni = (const float*)d_in[19];
  const float* gW_nj = (const float*)d_in[20];
  const float* gW_fij = (const float*)d_in[21];
  const float* g_attn = (const float*)d_in[22];
  const float* g_bias = (const float*)d_in[23];
  const float* agg2_W = (const float*)d_in[24];
  const float* agg2_b = (const float*)d_in[25];
  const float* lin1_ui_W = (const float*)d_in[26];
  const float* lin1_ui_b = (const float*)d_in[27];
  const float* lin2_ui_W = (const float*)d_in[28];
  const float* lin2_ui_b = (const float*)d_in[29];
  const float* lin1_sg_W = (const float*)d_in[30];
  const float* lin1_sg_b = (const float*)d_in[31];
  const float* lin2_sg_W = (const float*)d_in[32];
  const float* lin2_sg_b = (const float*)d_in[33];

  float* out = (float*)d_out;

  // workspace layout (floats)
  float* ws = (float*)d_ws;
  float* XN = ws;                       // [N,256]
  float* NI = XN + (size_t)NN * 256;    // [N,64]
  float* NJ = NI + (size_t)NN * 64;     // [N,64]
  float* HS = NJ + (size_t)NN * 64;     // [N,256]
  float* Xc = HS + (size_t)NN * 256;    // [N,64]
  float* EX = Xc + (size_t)NN * 64;     // [E,4]
  float* uiX = EX + (size_t)EE * 4;     // [B,384]
  float* sgX = uiX + (size_t)BB * 384;  // [B,192]
  int* rowp = (int*)(sgX + (size_t)BB * 192);  // [N+1]
  int* counts = rowp + (NN + 1);               // [N]
  int* eidx = counts + NN;                     // [E]

  // ---- CSR by dst (same graph for all 6 EGAT calls) ----
  hipMemsetAsync(counts, 0, NN * sizeof(int), stream);
  count_k<<<(EE + 255) / 256, 256, 0, stream>>>(dst, counts, EE);
  scan_k<<<1, 1024, 0, stream>>>(counts, rowp, NN);
  hipMemsetAsync(counts, 0, NN * sizeof(int), stream);
  fill_k<<<(EE + 255) / 256, 256, 0, stream>>>(dst, rowp, counts, eidx, EE);

  // x working copy
  hipMemcpyAsync(Xc, x_in, (size_t)NN * 64 * sizeof(float), hipMemcpyDeviceToDevice,
                 stream);

  dim3 gGemmN((NN + 63) / 64, 4);   // Ncol=256
  dim3 gGemm64((NN + 63) / 64, 1);  // Ncol=64
  int edgeBlocks = (EE + 3) / 4;

  for (int i = 0; i < LL; i++) {
    // ===== local EGAT =====
    gemm_k<0><<<gGemmN, 256, 0, stream>>>(Xc, lW_node + (size_t)i * 64 * 256, nullptr,
                                          XN, NN, 64, 256);
    gemm_k<0><<<gGemm64, 256, 0, stream>>>(Xc, lW_ni + (size_t)i * 64 * 64, nullptr, NI,
                                           NN, 64, 64);
    gemm_k<0><<<gGemm64, 256, 0, stream>>>(Xc, lW_nj + (size_t)i * 64 * 64, nullptr, NJ,
                                           NN, 64, 64);
    edge_k<8><<<edgeBlocks, 256, 0, stream>>>(NI, NJ, efeat, lW_fij + (size_t)i * 8 * 64,
                                              l_attn + (size_t)i * 64,
                                              l_bias + (size_t)i * 64, src, dst, EX, EE);
    node_agg_k<<<NN, 256, 0, stream>>>(XN, EX, mask, src, eidx, rowp, HS, NN);
    gemm_k<1><<<gGemm64, 256, 0, stream>>>(HS, agg1_W + (size_t)i * 256 * 64,
                                           agg1_b + (size_t)i * 64, Xc, NN, 256, 64);
    gather2_k<<<BB, 64, 0, stream>>>(Xc, user_idx, item_idx, uiX, i);

    // ===== global EGAT =====
    gemm_k<0><<<gGemmN, 256, 0, stream>>>(Xc, gW_node + (size_t)i * 64 * 256, nullptr,
                                          XN, NN, 64, 256);
    gemm_k<0><<<gGemm64, 256, 0, stream>>>(Xc, gW_ni + (size_t)i * 64 * 64, nullptr, NI,
                                           NN, 64, 64);
    gemm_k<0><<<gGemm64, 256, 0, stream>>>(Xc, gW_nj + (size_t)i * 64 * 64, nullptr, NJ,
                                           NN, 64, 64);
    edge_k<64><<<edgeBlocks, 256, 0, stream>>>(
        NI, NJ, efeat2, gW_fij + (size_t)i * 64 * 64, g_attn + (size_t)i * 64,
        g_bias + (size_t)i * 64, src, dst, EX, EE);
    node_agg_k<<<NN, 256, 0, stream>>>(XN, EX, mask2, src, eidx, rowp, HS, NN);
    gemm_k<2><<<gGemm64, 256, 0, stream>>>(HS, agg2_W + (size_t)i * 256 * 64,
                                           agg2_b + (size_t)i * 64, Xc, NN, 256, 64);
    gather1_k<<<BB, 64, 0, stream>>>(Xc, subg_idx, sgX, i);
  }

  // ===== heads =====  output order: (subg_o, ui_o)
  head_k<<<BB, 128, 0, stream>>>(sgX, lin1_sg_W, lin1_sg_b, lin2_sg_W, lin2_sg_b, out,
                                 192);
  head_k<<<BB, 128, 0, stream>>>(uiX, lin1_ui_W, lin1_ui_b, lin2_ui_W, lin2_ui_b,
                                 out + BB, 384);
}

// Round 2
// 4344.450 us; speedup vs baseline: 1.1606x; 1.1606x over previous
//
#include <hip/hip_runtime.h>

#define NN 60000
#define EE 600000
#define BB 1024
#define LL 3

// ---------------- CSR construction ----------------

__global__ __launch_bounds__(256) void count_k(const int* __restrict__ dst,
                                               int* __restrict__ counts, int E_) {
  int e = blockIdx.x * 256 + threadIdx.x;
  if (e < E_) atomicAdd(&counts[dst[e]], 1);
}

__global__ __launch_bounds__(1024) void scan_k(const int* __restrict__ counts,
                                               int* __restrict__ rowp, int Nn) {
  __shared__ int part[1024];
  int t = threadIdx.x;
  int per = (Nn + 1023) >> 10;
  int b = t * per;
  int sum = 0;
  for (int i = 0; i < per; i++) {
    int idx = b + i;
    if (idx < Nn) sum += counts[idx];
  }
  part[t] = sum;
  for (int off = 1; off < 1024; off <<= 1) {
    __syncthreads();
    int v = (t >= off) ? part[t - off] : 0;
    __syncthreads();
    part[t] += v;
  }
  __syncthreads();
  int run = part[t] - sum;  // exclusive prefix
  for (int i = 0; i < per; i++) {
    int idx = b + i;
    if (idx < Nn) {
      rowp[idx] = run;
      run += counts[idx];
    }
  }
  if (t == 1023) rowp[Nn] = part[1023];
}

__global__ __launch_bounds__(256) void fill_k(const int* __restrict__ dst,
                                              const int* __restrict__ rowp,
                                              int* __restrict__ cursor,
                                              int* __restrict__ eidx, int E_) {
  int e = blockIdx.x * 256 + threadIdx.x;
  if (e >= E_) return;
  int d = dst[e];
  int pos = atomicAdd(&cursor[d], 1);
  eidx[rowp[d] + pos] = e;
}

// ---------------- fused projection: P[N,384] = A @ [Wn | Wni | Wnj] ----------------
// cols 0..255 = x@Wn, 256..319 = x@Wni, 320..383 = x@Wnj. A-tile loaded once.

__global__ __launch_bounds__(256) void proj_k(const float* __restrict__ A,
                                              const float* __restrict__ Wn,
                                              const float* __restrict__ Wni,
                                              const float* __restrict__ Wnj,
                                              float* __restrict__ P, int M) {
  __shared__ float As[64][65];
  __shared__ float Bs[64][65];
  int row0 = blockIdx.x * 64;
  int c = threadIdx.x & 63;
  int rg = threadIdx.x >> 6;
#pragma unroll
  for (int i = 0; i < 16; i++) {
    int idx = threadIdx.x + i * 256;
    int r = idx >> 6, kk = idx & 63;
    As[r][kk] = (row0 + r < M) ? A[(size_t)(row0 + r) * 64 + kk] : 0.f;
  }
  for (int cb = 0; cb < 6; cb++) {
    const float* B = cb < 4 ? Wn : (cb == 4 ? Wni : Wnj);
    int bcol = cb < 4 ? cb * 64 : 0;
    int bld = cb < 4 ? 256 : 64;
    __syncthreads();  // protects Bs from previous iteration's readers (and As on cb=0)
#pragma unroll
    for (int i = 0; i < 16; i++) {
      int idx = threadIdx.x + i * 256;
      int kk = idx >> 6, cc = idx & 63;
      Bs[kk][cc] = B[(size_t)kk * bld + bcol + cc];
    }
    __syncthreads();
    float acc[16];
#pragma unroll
    for (int i = 0; i < 16; i++) acc[i] = 0.f;
#pragma unroll 16
    for (int kk = 0; kk < 64; kk++) {
      float bv = Bs[kk][c];
#pragma unroll
      for (int i = 0; i < 16; i++) acc[i] += As[rg * 16 + i][kk] * bv;
    }
#pragma unroll
    for (int i = 0; i < 16; i++) {
      int r = row0 + rg * 16 + i;
      if (r < M) P[(size_t)r * 384 + cb * 64 + c] = acc[i];
    }
  }
}

// ---------------- generic fp32 GEMM: C = act(A[M,K] @ B[K,Ncol] + bias) ----------------
// ACT: 0 = none, 1 = ELU (alpha=1), 2 = leaky_relu(0.01)

template <int ACT>
__global__ __launch_bounds__(256) void gemm_k(const float* __restrict__ A,
                                              const float* __restrict__ B,
                                              const float* __restrict__ bias,
                                              float* __restrict__ C, int M, int K,
                                              int Ncol) {
  __shared__ float As[64][65];
  __shared__ float Bs[64][65];
  int row0 = blockIdx.x * 64;
  int col0 = blockIdx.y * 64;
  int c = threadIdx.x & 63;
  int rg = threadIdx.x >> 6;
  float acc[16];
#pragma unroll
  for (int i = 0; i < 16; i++) acc[i] = 0.f;

  for (int k0 = 0; k0 < K; k0 += 64) {
#pragma unroll
    for (int i = 0; i < 16; i++) {
      int idx = threadIdx.x + i * 256;
      int r = idx >> 6, kk = idx & 63;
      As[r][kk] = (row0 + r < M) ? A[(size_t)(row0 + r) * K + k0 + kk] : 0.f;
    }
#pragma unroll
    for (int i = 0; i < 16; i++) {
      int idx = threadIdx.x + i * 256;
      int kk = idx >> 6, cc = idx & 63;
      Bs[kk][cc] = B[(size_t)(k0 + kk) * Ncol + col0 + cc];
    }
    __syncthreads();
#pragma unroll 16
    for (int kk = 0; kk < 64; kk++) {
      float bv = Bs[kk][c];
#pragma unroll
      for (int i = 0; i < 16; i++) acc[i] += As[rg * 16 + i][kk] * bv;
    }
    __syncthreads();
  }
#pragma unroll
  for (int i = 0; i < 16; i++) {
    int r = row0 + rg * 16 + i;
    if (r < M) {
      float v = acc[i] + (bias ? bias[col0 + c] : 0.f);
      if (ACT == 1) v = v > 0.f ? v : expm1f(v);
      if (ACT == 2) v = v > 0.f ? v : 0.01f * v;
      C[(size_t)r * Ncol + col0 + c] = v;
    }
  }
}

// ---------------- edge kernel: attention logits -> exp ----------------
// Persistent grid-stride; one wave per edge; lane = column of H*FE=64.
// Wf column held in 64 VGPRs per lane (loaded once). ef broadcast via wave-local LDS.

template <int K>
__global__ __launch_bounds__(256) void edge_k(const float* __restrict__ P,
                                              const float* __restrict__ EF,
                                              const float* __restrict__ Wf,
                                              const float* __restrict__ attn,
                                              const float* __restrict__ bias,
                                              const int* __restrict__ src,
                                              const int* __restrict__ dst,
                                              float* __restrict__ EX, int E_) {
  __shared__ float efs[4][K];
  int c = threadIdx.x & 63;
  int le = threadIdx.x >> 6;
  float wreg[K];
#pragma unroll
  for (int k = 0; k < K; k++) wreg[k] = Wf[k * 64 + c];
  float att = attn[c];
  float bi = bias[c];
  int ngroups = (E_ + 3) >> 2;
  for (int g = blockIdx.x; g < ngroups; g += gridDim.x) {
    int e = g * 4 + le;
    if (e >= E_) continue;
    int s = src[e], d = dst[e];
    if (c < K) efs[le][c] = EF[(size_t)e * K + c];
    float f0 = P[(size_t)s * 384 + 256 + c] + P[(size_t)d * 384 + 320 + c] + bi;
    float f1 = 0.f, f2 = 0.f, f3 = 0.f;
#pragma unroll
    for (int k = 0; k < K; k += 4) {
      float4 ev = *(const float4*)&efs[le][k];
      f0 += ev.x * wreg[k];
      f1 += ev.y * wreg[k + 1];
      f2 += ev.z * wreg[k + 2];
      f3 += ev.w * wreg[k + 3];
    }
    float f = (f0 + f1) + (f2 + f3);
    f = f > 0.f ? f : 0.01f * f;
    float v = f * att;
    v += __shfl_xor(v, 1);
    v += __shfl_xor(v, 2);
    v += __shfl_xor(v, 4);
    v += __shfl_xor(v, 8);
    if ((c & 15) == 0) EX[(size_t)e * 4 + (c >> 4)] = __expf(v);
  }
}

// ---------------- per-destination-node aggregation ----------------
// 1 block = 1 node; 256 threads = (h,d) accumulator grid. P row stride = 384.
// out[n,h,d] = sum_e ex*mask*P[src,h*64+d] / sum_e ex   (0 if no edges)

__global__ __launch_bounds__(256) void node_agg_k(const float* __restrict__ P,
                                                  const float* __restrict__ EX,
                                                  const float* __restrict__ mask,
                                                  const int* __restrict__ srcArr,
                                                  const int* __restrict__ eidx,
                                                  const int* __restrict__ rowp,
                                                  float* __restrict__ HS, int Nn) {
  int n = blockIdx.x;
  int t = threadIdx.x;
  int h = t >> 6;
  int beg = rowp[n], end = rowp[n + 1];
  float acc = 0.f, ssum = 0.f;
  if (beg < end) {
    int e = eidx[beg];
    int s = srcArr[e];
    float ex = EX[(size_t)e * 4 + h];
    float mk = mask[e];
    for (int i = beg + 1; i < end; i++) {
      int e2 = eidx[i];
      int s2 = srcArr[e2];
      float ex2 = EX[(size_t)e2 * 4 + h];
      float mk2 = mask[e2];
      acc += ex * mk * P[(size_t)s * 384 + t];
      ssum += ex;
      e = e2; s = s2; ex = ex2; mk = mk2;
    }
    acc += ex * mk * P[(size_t)s * 384 + t];
    ssum += ex;
  }
  HS[(size_t)n * 256 + t] = (ssum > 0.f) ? acc / ssum : 0.f;
}

// ---------------- gathers into head feature matrices ----------------

__global__ __launch_bounds__(64) void gather2_k(const float* __restrict__ X,
                                                const int* __restrict__ uidx,
                                                const int* __restrict__ iidx,
                                                float* __restrict__ uiX, int layer) {
  int b = blockIdx.x;
  int c = threadIdx.x;
  uiX[(size_t)b * 384 + layer * 64 + c] = X[(size_t)uidx[b] * 64 + c];
  uiX[(size_t)b * 384 + 192 + layer * 64 + c] = X[(size_t)iidx[b] * 64 + c];
}

__global__ __launch_bounds__(64) void gather1_k(const float* __restrict__ X,
                                                const int* __restrict__ sidx,
                                                float* __restrict__ sgX, int layer) {
  int b = blockIdx.x;
  int c = threadIdx.x;
  sgX[(size_t)b * 192 + layer * 64 + c] = X[(size_t)sidx[b] * 64 + c];
}

// ---------------- head MLP: sigmoid(relu(X@W1+b1)@W2+b2) ----------------

__global__ __launch_bounds__(128) void head_k(const float* __restrict__ Xf,
                                              const float* __restrict__ W1,
                                              const float* __restrict__ b1,
                                              const float* __restrict__ W2,
                                              const float* __restrict__ b2,
                                              float* __restrict__ out, int F) {
  __shared__ float xs[384];
  __shared__ float red[128];
  int b = blockIdx.x, t = threadIdx.x;
  for (int i = t; i < F; i += 128) xs[i] = Xf[(size_t)b * F + i];
  __syncthreads();
  float acc = b1[t];
  for (int k = 0; k < F; k++) acc += xs[k] * W1[k * 128 + t];
  acc = fmaxf(acc, 0.f);
  float v = acc * W2[t];
  v += __shfl_xor(v, 1);
  v += __shfl_xor(v, 2);
  v += __shfl_xor(v, 4);
  v += __shfl_xor(v, 8);
  v += __shfl_xor(v, 16);
  v += __shfl_xor(v, 32);
  red[t] = v;
  __syncthreads();
  if (t == 0) {
    float tot = red[0] + red[64] + b2[0];
    out[b] = 1.f / (1.f + __expf(-tot));
  }
}

// ---------------- driver ----------------

extern "C" void kernel_launch(void* const* d_in, const int* in_sizes, int n_in,
                              void* d_out, int out_size, void* d_ws, size_t ws_size,
                              hipStream_t stream) {
  const float* x_in = (const float*)d_in[0];
  const float* efeat = (const float*)d_in[1];
  const float* efeat2 = (const float*)d_in[2];
  const float* mask = (const float*)d_in[3];
  const float* mask2 = (const float*)d_in[4];
  const int* src = (const int*)d_in[5];
  const int* dst = (const int*)d_in[6];
  const int* user_idx = (const int*)d_in[7];
  const int* item_idx = (const int*)d_in[8];
  const int* subg_idx = (const int*)d_in[9];
  const float* lW_node = (const float*)d_in[10];
  const float* lW_ni = (const float*)d_in[11];
  const float* lW_nj = (const float*)d_in[12];
  const float* lW_fij = (const float*)d_in[13];
  const float* l_attn = (const float*)d_in[14];
  const float* l_bias = (const float*)d_in[15];
  const float* agg1_W = (const float*)d_in[16];
  const float* agg1_b = (const float*)d_in[17];
  const float* gW_node = (const float*)d_in[18];
  const float* gW_ni = (const float*)d_in[19];
  const float* gW_nj = (const float*)d_in[20];
  const float* gW_fij = (const float*)d_in[21];
  const float* g_attn = (const float*)d_in[22];
  const float* g_bias = (const float*)d_in[23];
  const float* agg2_W = (const float*)d_in[24];
  const float* agg2_b = (const float*)d_in[25];
  const float* lin1_ui_W = (const float*)d_in[26];
  const float* lin1_ui_b = (const float*)d_in[27];
  const float* lin2_ui_W = (const float*)d_in[28];
  const float* lin2_ui_b = (const float*)d_in[29];
  const float* lin1_sg_W = (const float*)d_in[30];
  const float* lin1_sg_b = (const float*)d_in[31];
  const float* lin2_sg_W = (const float*)d_in[32];
  const float* lin2_sg_b = (const float*)d_in[33];

  float* out = (float*)d_out;

  // workspace layout (floats) — same total as round 1
  float* ws = (float*)d_ws;
  float* P = ws;                         // [N,384]: XN | NI | NJ
  float* HS = P + (size_t)NN * 384;      // [N,256]
  float* Xc = HS + (size_t)NN * 256;     // [N,64]
  float* EX = Xc + (size_t)NN * 64;      // [E,4]
  float* uiX = EX + (size_t)EE * 4;      // [B,384]
  float* sgX = uiX + (size_t)BB * 384;   // [B,192]
  int* rowp = (int*)(sgX + (size_t)BB * 192);  // [N+1]
  int* counts = rowp + (NN + 1);               // [N]
  int* eidx = counts + NN;                     // [E]

  // ---- CSR by dst (same graph for all 6 EGAT calls) ----
  hipMemsetAsync(counts, 0, NN * sizeof(int), stream);
  count_k<<<(EE + 255) / 256, 256, 0, stream>>>(dst, counts, EE);
  scan_k<<<1, 1024, 0, stream>>>(counts, rowp, NN);
  hipMemsetAsync(counts, 0, NN * sizeof(int), stream);
  fill_k<<<(EE + 255) / 256, 256, 0, stream>>>(dst, rowp, counts, eidx, EE);

  // x working copy
  hipMemcpyAsync(Xc, x_in, (size_t)NN * 64 * sizeof(float), hipMemcpyDeviceToDevice,
                 stream);

  int gProj = (NN + 63) / 64;
  dim3 gAgg((NN + 63) / 64, 1);  // K=256 -> Ncol=64
  int edgeBlocks = 2048;

  for (int i = 0; i < LL; i++) {
    // ===== local EGAT =====
    proj_k<<<gProj, 256, 0, stream>>>(Xc, lW_node + (size_t)i * 64 * 256,
                                      lW_ni + (size_t)i * 64 * 64,
                                      lW_nj + (size_t)i * 64 * 64, P, NN);
    edge_k<8><<<edgeBlocks, 256, 0, stream>>>(P, efeat, lW_fij + (size_t)i * 8 * 64,
                                              l_attn + (size_t)i * 64,
                                              l_bias + (size_t)i * 64, src, dst, EX, EE);
    node_agg_k<<<NN, 256, 0, stream>>>(P, EX, mask, src, eidx, rowp, HS, NN);
    gemm_k<1><<<gAgg, 256, 0, stream>>>(HS, agg1_W + (size_t)i * 256 * 64,
                                        agg1_b + (size_t)i * 64, Xc, NN, 256, 64);
    gather2_k<<<BB, 64, 0, stream>>>(Xc, user_idx, item_idx, uiX, i);

    // ===== global EGAT =====
    proj_k<<<gProj, 256, 0, stream>>>(Xc, gW_node + (size_t)i * 64 * 256,
                                      gW_ni + (size_t)i * 64 * 64,
                                      gW_nj + (size_t)i * 64 * 64, P, NN);
    edge_k<64><<<edgeBlocks, 256, 0, stream>>>(
        P, efeat2, gW_fij + (size_t)i * 64 * 64, g_attn + (size_t)i * 64,
        g_bias + (size_t)i * 64, src, dst, EX, EE);
    node_agg_k<<<NN, 256, 0, stream>>>(P, EX, mask2, src, eidx, rowp, HS, NN);
    gemm_k<2><<<gAgg, 256, 0, stream>>>(HS, agg2_W + (size_t)i * 256 * 64,
                                        agg2_b + (size_t)i * 64, Xc, NN, 256, 64);
    gather1_k<<<BB, 64, 0, stream>>>(Xc, subg_idx, sgX, i);
  }

  // ===== heads =====  output order: (subg_o, ui_o)
  head_k<<<BB, 128, 0, stream>>>(sgX, lin1_sg_W, lin1_sg_b, lin2_sg_W, lin2_sg_b, out,
                                 192);
  head_k<<<BB, 128, 0, stream>>>(uiX, lin1_ui_W, lin1_ui_b, lin2_ui_W, lin2_ui_b,
                                 out + BB, 384);
}

// Round 3
// 4017.023 us; speedup vs baseline: 1.2552x; 1.0815x over previous
//
#include <hip/hip_runtime.h>

#define NN 60000
#define EE 600000
#define BB 1024
#define LL 3

// ---------------- CSR construction ----------------

__global__ __launch_bounds__(256) void count_k(const int* __restrict__ dst,
                                               int* __restrict__ counts, int E_) {
  int e = blockIdx.x * 256 + threadIdx.x;
  if (e < E_) atomicAdd(&counts[dst[e]], 1);
}

__global__ __launch_bounds__(1024) void scan_k(const int* __restrict__ counts,
                                               int* __restrict__ rowp, int Nn) {
  __shared__ int part[1024];
  int t = threadIdx.x;
  int per = (Nn + 1023) >> 10;
  int b = t * per;
  int sum = 0;
  for (int i = 0; i < per; i++) {
    int idx = b + i;
    if (idx < Nn) sum += counts[idx];
  }
  part[t] = sum;
  for (int off = 1; off < 1024; off <<= 1) {
    __syncthreads();
    int v = (t >= off) ? part[t - off] : 0;
    __syncthreads();
    part[t] += v;
  }
  __syncthreads();
  int run = part[t] - sum;  // exclusive prefix
  for (int i = 0; i < per; i++) {
    int idx = b + i;
    if (idx < Nn) {
      rowp[idx] = run;
      run += counts[idx];
    }
  }
  if (t == 1023) rowp[Nn] = part[1023];
}

__global__ __launch_bounds__(256) void fill_k(const int* __restrict__ dst,
                                              const int* __restrict__ rowp,
                                              int* __restrict__ cursor,
                                              int* __restrict__ eidx, int E_) {
  int e = blockIdx.x * 256 + threadIdx.x;
  if (e >= E_) return;
  int d = dst[e];
  int pos = atomicAdd(&cursor[d], 1);
  eidx[rowp[d] + pos] = e;
}

// ---------------- weight fold: Wq[k, h*64+j] = sum_d Wn[k,h*64+d]*aggW[h*64+d,j] ----
// 4 blocks (one per head), 256 threads each. Wq is [64,256] row-major.

__global__ __launch_bounds__(256) void wq_k(const float* __restrict__ Wn,
                                            const float* __restrict__ aggW,
                                            float* __restrict__ Wq) {
  __shared__ float A[64][65];   // A[k][d]
  __shared__ float Bm[64][65];  // B[d][j]
  int h = blockIdx.x;
  int t = threadIdx.x;
  for (int idx = t; idx < 4096; idx += 256) {
    int k = idx >> 6, d = idx & 63;
    A[k][d] = Wn[k * 256 + h * 64 + d];
  }
  for (int idx = t; idx < 4096; idx += 256) {
    int d = idx >> 6, j = idx & 63;
    Bm[d][j] = aggW[(h * 64 + d) * 64 + j];
  }
  __syncthreads();
  int j = t & 63, rg = t >> 6;
#pragma unroll
  for (int i = 0; i < 16; i++) {
    int k = rg * 16 + i;
    float acc = 0.f;
#pragma unroll 16
    for (int d = 0; d < 64; d++) acc += A[k][d] * Bm[d][j];
    Wq[k * 256 + h * 64 + j] = acc;
  }
}

// ---------------- fused projection: P[N,384] = A @ [Wq | Wni | Wnj] ----------------
// cols 0..255 = x@Wq (per-head pre-agg'd), 256..319 = x@Wni, 320..383 = x@Wnj.

__global__ __launch_bounds__(256) void proj_k(const float* __restrict__ A,
                                              const float* __restrict__ Wq,
                                              const float* __restrict__ Wni,
                                              const float* __restrict__ Wnj,
                                              float* __restrict__ P, int M) {
  __shared__ float As[64][65];
  __shared__ float Bs[64][65];
  int row0 = blockIdx.x * 64;
  int c = threadIdx.x & 63;
  int rg = threadIdx.x >> 6;
#pragma unroll
  for (int i = 0; i < 16; i++) {
    int idx = threadIdx.x + i * 256;
    int r = idx >> 6, kk = idx & 63;
    As[r][kk] = (row0 + r < M) ? A[(size_t)(row0 + r) * 64 + kk] : 0.f;
  }
  for (int cb = 0; cb < 6; cb++) {
    const float* B = cb < 4 ? Wq : (cb == 4 ? Wni : Wnj);
    int bcol = cb < 4 ? cb * 64 : 0;
    int bld = cb < 4 ? 256 : 64;
    __syncthreads();  // protects Bs from previous iteration's readers (and As on cb=0)
#pragma unroll
    for (int i = 0; i < 16; i++) {
      int idx = threadIdx.x + i * 256;
      int kk = idx >> 6, cc = idx & 63;
      Bs[kk][cc] = B[(size_t)kk * bld + bcol + cc];
    }
    __syncthreads();
    float acc[16];
#pragma unroll
    for (int i = 0; i < 16; i++) acc[i] = 0.f;
#pragma unroll 16
    for (int kk = 0; kk < 64; kk++) {
      float bv = Bs[kk][c];
#pragma unroll
      for (int i = 0; i < 16; i++) acc[i] += As[rg * 16 + i][kk] * bv;
    }
#pragma unroll
    for (int i = 0; i < 16; i++) {
      int r = row0 + rg * 16 + i;
      if (r < M) P[(size_t)r * 384 + cb * 64 + c] = acc[i];
    }
  }
}

// ---------------- edge kernel: attention logits -> exp ----------------
// Persistent grid-stride; one wave per edge; lane = column of H*FE=64.
// Wf column in 64 VGPRs per lane; ef row read via SCALAR loads (e is wave-uniform,
// forced into SGPR with readfirstlane) -> inner loop is pure v_fmac, zero LDS.

template <int K>
__global__ __launch_bounds__(256) void edge_k(const float* __restrict__ P,
                                              const float* __restrict__ EF,
                                              const float* __restrict__ Wf,
                                              const float* __restrict__ attn,
                                              const float* __restrict__ bias,
                                              const int* __restrict__ src,
                                              const int* __restrict__ dst,
                                              float* __restrict__ EX, int E_) {
  int c = threadIdx.x & 63;
  int le = threadIdx.x >> 6;
  float wreg[K];
#pragma unroll
  for (int k = 0; k < K; k++) wreg[k] = Wf[k * 64 + c];
  float att = attn[c];
  float bi = bias[c];
  int ngroups = (E_ + 3) >> 2;
  for (int g = blockIdx.x; g < ngroups; g += gridDim.x) {
    int e = g * 4 + le;
    if (e >= E_) continue;
    int eu = __builtin_amdgcn_readfirstlane(e);  // wave-uniform edge id -> SGPR
    int s = src[eu], d = dst[eu];                // scalar loads
    const float* efr = EF + (size_t)eu * K;      // uniform base -> s_load rows
    float f0 = P[(size_t)s * 384 + 256 + c] + P[(size_t)d * 384 + 320 + c] + bi;
    float f1 = 0.f, f2 = 0.f, f3 = 0.f;
#pragma unroll
    for (int k = 0; k < K; k += 4) {
      f0 += efr[k] * wreg[k];
      f1 += efr[k + 1] * wreg[k + 1];
      f2 += efr[k + 2] * wreg[k + 2];
      f3 += efr[k + 3] * wreg[k + 3];
    }
    float f = (f0 + f1) + (f2 + f3);
    f = f > 0.f ? f : 0.01f * f;
    float v = f * att;
    v += __shfl_xor(v, 1);
    v += __shfl_xor(v, 2);
    v += __shfl_xor(v, 4);
    v += __shfl_xor(v, 8);
    if ((c & 15) == 0) EX[(size_t)e * 4 + (c >> 4)] = __expf(v);
  }
}

// ---------------- per-destination-node aggregation + folded agg-GEMM epilogue -------
// 1 block = 1 node; 256 threads = (h,j) grid over Q = x@Wq.
// acc[h,j] = sum_e ex*mask*Q[src, h*64+j] / sum_e ex ; out[n,j] = act(sum_h acc + b[j])
// ACT: 1 = ELU, 2 = leaky_relu(0.01)

template <int ACT>
__global__ __launch_bounds__(256) void node_agg_k(const float* __restrict__ P,
                                                  const float* __restrict__ EX,
                                                  const float* __restrict__ mask,
                                                  const int* __restrict__ srcArr,
                                                  const int* __restrict__ eidx,
                                                  const int* __restrict__ rowp,
                                                  const float* __restrict__ bias,
                                                  float* __restrict__ Xout, int Nn) {
  __shared__ float sdata[256];
  int n = blockIdx.x;
  int t = threadIdx.x;
  int h = t >> 6;
  int beg = rowp[n], end = rowp[n + 1];
  float acc = 0.f, ssum = 0.f;
  if (beg < end) {
    int e = eidx[beg];
    int s = srcArr[e];
    float ex = EX[(size_t)e * 4 + h];
    float mk = mask[e];
    for (int i = beg + 1; i < end; i++) {
      int e2 = eidx[i];
      int s2 = srcArr[e2];
      float ex2 = EX[(size_t)e2 * 4 + h];
      float mk2 = mask[e2];
      acc += ex * mk * P[(size_t)s * 384 + t];
      ssum += ex;
      e = e2; s = s2; ex = ex2; mk = mk2;
    }
    acc += ex * mk * P[(size_t)s * 384 + t];
    ssum += ex;
  }
  sdata[t] = (ssum > 0.f) ? acc / ssum : 0.f;
  __syncthreads();
  if (t < 64) {
    float v = sdata[t] + sdata[t + 64] + sdata[t + 128] + sdata[t + 192] + bias[t];
    if (ACT == 1) v = v > 0.f ? v : expm1f(v);
    else v = v > 0.f ? v : 0.01f * v;
    Xout[(size_t)n * 64 + t] = v;
  }
}

// ---------------- gathers into head feature matrices ----------------

__global__ __launch_bounds__(64) void gather2_k(const float* __restrict__ X,
                                                const int* __restrict__ uidx,
                                                const int* __restrict__ iidx,
                                                float* __restrict__ uiX, int layer) {
  int b = blockIdx.x;
  int c = threadIdx.x;
  uiX[(size_t)b * 384 + layer * 64 + c] = X[(size_t)uidx[b] * 64 + c];
  uiX[(size_t)b * 384 + 192 + layer * 64 + c] = X[(size_t)iidx[b] * 64 + c];
}

__global__ __launch_bounds__(64) void gather1_k(const float* __restrict__ X,
                                                const int* __restrict__ sidx,
                                                float* __restrict__ sgX, int layer) {
  int b = blockIdx.x;
  int c = threadIdx.x;
  sgX[(size_t)b * 192 + layer * 64 + c] = X[(size_t)sidx[b] * 64 + c];
}

// ---------------- head MLP: sigmoid(relu(X@W1+b1)@W2+b2) ----------------

__global__ __launch_bounds__(128) void head_k(const float* __restrict__ Xf,
                                              const float* __restrict__ W1,
                                              const float* __restrict__ b1,
                                              const float* __restrict__ W2,
                                              const float* __restrict__ b2,
                                              float* __restrict__ out, int F) {
  __shared__ float xs[384];
  __shared__ float red[128];
  int b = blockIdx.x, t = threadIdx.x;
  for (int i = t; i < F; i += 128) xs[i] = Xf[(size_t)b * F + i];
  __syncthreads();
  float acc = b1[t];
  for (int k = 0; k < F; k++) acc += xs[k] * W1[k * 128 + t];
  acc = fmaxf(acc, 0.f);
  float v = acc * W2[t];
  v += __shfl_xor(v, 1);
  v += __shfl_xor(v, 2);
  v += __shfl_xor(v, 4);
  v += __shfl_xor(v, 8);
  v += __shfl_xor(v, 16);
  v += __shfl_xor(v, 32);
  red[t] = v;
  __syncthreads();
  if (t == 0) {
    float tot = red[0] + red[64] + b2[0];
    out[b] = 1.f / (1.f + __expf(-tot));
  }
}

// ---------------- driver ----------------

extern "C" void kernel_launch(void* const* d_in, const int* in_sizes, int n_in,
                              void* d_out, int out_size, void* d_ws, size_t ws_size,
                              hipStream_t stream) {
  const float* x_in = (const float*)d_in[0];
  const float* efeat = (const float*)d_in[1];
  const float* efeat2 = (const float*)d_in[2];
  const float* mask = (const float*)d_in[3];
  const float* mask2 = (const float*)d_in[4];
  const int* src = (const int*)d_in[5];
  const int* dst = (const int*)d_in[6];
  const int* user_idx = (const int*)d_in[7];
  const int* item_idx = (const int*)d_in[8];
  const int* subg_idx = (const int*)d_in[9];
  const float* lW_node = (const float*)d_in[10];
  const float* lW_ni = (const float*)d_in[11];
  const float* lW_nj = (const float*)d_in[12];
  const float* lW_fij = (const float*)d_in[13];
  const float* l_attn = (const float*)d_in[14];
  const float* l_bias = (const float*)d_in[15];
  const float* agg1_W = (const float*)d_in[16];
  const float* agg1_b = (const float*)d_in[17];
  const float* gW_node = (const float*)d_in[18];
  const float* gW_ni = (const float*)d_in[19];
  const float* gW_nj = (const float*)d_in[20];
  const float* gW_fij = (const float*)d_in[21];
  const float* g_attn = (const float*)d_in[22];
  const float* g_bias = (const float*)d_in[23];
  const float* agg2_W = (const float*)d_in[24];
  const float* agg2_b = (const float*)d_in[25];
  const float* lin1_ui_W = (const float*)d_in[26];
  const float* lin1_ui_b = (const float*)d_in[27];
  const float* lin2_ui_W = (const float*)d_in[28];
  const float* lin2_ui_b = (const float*)d_in[29];
  const float* lin1_sg_W = (const float*)d_in[30];
  const float* lin1_sg_b = (const float*)d_in[31];
  const float* lin2_sg_W = (const float*)d_in[32];
  const float* lin2_sg_b = (const float*)d_in[33];

  float* out = (float*)d_out;

  // workspace layout (floats)
  float* ws = (float*)d_ws;
  float* P = ws;                         // [N,384]: Q | NI | NJ
  float* Xc = P + (size_t)NN * 384;      // [N,64]
  float* EX = Xc + (size_t)NN * 64;      // [E,4]
  float* Wq = EX + (size_t)EE * 4;       // [64,256]
  float* uiX = Wq + 64 * 256;            // [B,384]
  float* sgX = uiX + (size_t)BB * 384;   // [B,192]
  int* rowp = (int*)(sgX + (size_t)BB * 192);  // [N+1]
  int* counts = rowp + (NN + 1);               // [N]
  int* eidx = counts + NN;                     // [E]

  // ---- CSR by dst (same graph for all 6 EGAT calls) ----
  hipMemsetAsync(counts, 0, NN * sizeof(int), stream);
  count_k<<<(EE + 255) / 256, 256, 0, stream>>>(dst, counts, EE);
  scan_k<<<1, 1024, 0, stream>>>(counts, rowp, NN);
  hipMemsetAsync(counts, 0, NN * sizeof(int), stream);
  fill_k<<<(EE + 255) / 256, 256, 0, stream>>>(dst, rowp, counts, eidx, EE);

  // x working copy
  hipMemcpyAsync(Xc, x_in, (size_t)NN * 64 * sizeof(float), hipMemcpyDeviceToDevice,
                 stream);

  int gProj = (NN + 63) / 64;
  int edgeBlocks = 2048;

  for (int i = 0; i < LL; i++) {
    // ===== local EGAT =====
    wq_k<<<4, 256, 0, stream>>>(lW_node + (size_t)i * 64 * 256,
                                agg1_W + (size_t)i * 256 * 64, Wq);
    proj_k<<<gProj, 256, 0, stream>>>(Xc, Wq, lW_ni + (size_t)i * 64 * 64,
                                      lW_nj + (size_t)i * 64 * 64, P, NN);
    edge_k<8><<<edgeBlocks, 256, 0, stream>>>(P, efeat, lW_fij + (size_t)i * 8 * 64,
                                              l_attn + (size_t)i * 64,
                                              l_bias + (size_t)i * 64, src, dst, EX, EE);
    node_agg_k<1><<<NN, 256, 0, stream>>>(P, EX, mask, src, eidx, rowp,
                                          agg1_b + (size_t)i * 64, Xc, NN);
    gather2_k<<<BB, 64, 0, stream>>>(Xc, user_idx, item_idx, uiX, i);

    // ===== global EGAT =====
    wq_k<<<4, 256, 0, stream>>>(gW_node + (size_t)i * 64 * 256,
                                agg2_W + (size_t)i * 256 * 64, Wq);
    proj_k<<<gProj, 256, 0, stream>>>(Xc, Wq, gW_ni + (size_t)i * 64 * 64,
                                      gW_nj + (size_t)i * 64 * 64, P, NN);
    edge_k<64><<<edgeBlocks, 256, 0, stream>>>(
        P, efeat2, gW_fij + (size_t)i * 64 * 64, g_attn + (size_t)i * 64,
        g_bias + (size_t)i * 64, src, dst, EX, EE);
    node_agg_k<2><<<NN, 256, 0, stream>>>(P, EX, mask2, src, eidx, rowp,
                                          agg2_b + (size_t)i * 64, Xc, NN);
    gather1_k<<<BB, 64, 0, stream>>>(Xc, subg_idx, sgX, i);
  }

  // ===== heads =====  output order: (subg_o, ui_o)
  head_k<<<BB, 128, 0, stream>>>(sgX, lin1_sg_W, lin1_sg_b, lin2_sg_W, lin2_sg_b, out,
                                 192);
  head_k<<<BB, 128, 0, stream>>>(uiX, lin1_ui_W, lin1_ui_b, lin2_ui_W, lin2_ui_b,
                                 out + BB, 384);
}

// Round 5
// 2973.840 us; speedup vs baseline: 1.6955x; 1.3508x over previous
//
#include <hip/hip_runtime.h>

#define NN 60000
#define EE 600000
#define BB 1024
#define LL 3

// ---------------- CSR construction ----------------

__global__ __launch_bounds__(256) void count_k(const int* __restrict__ dst,
                                               int* __restrict__ counts, int E_) {
  int e = blockIdx.x * 256 + threadIdx.x;
  if (e < E_) atomicAdd(&counts[dst[e]], 1);
}

__global__ __launch_bounds__(1024) void scan_k(const int* __restrict__ counts,
                                               int* __restrict__ rowp, int Nn) {
  __shared__ int part[1024];
  int t = threadIdx.x;
  int per = (Nn + 1023) >> 10;
  int b = t * per;
  int sum = 0;
  for (int i = 0; i < per; i++) {
    int idx = b + i;
    if (idx < Nn) sum += counts[idx];
  }
  part[t] = sum;
  for (int off = 1; off < 1024; off <<= 1) {
    __syncthreads();
    int v = (t >= off) ? part[t - off] : 0;
    __syncthreads();
    part[t] += v;
  }
  __syncthreads();
  int run = part[t] - sum;  // exclusive prefix
  for (int i = 0; i < per; i++) {
    int idx = b + i;
    if (idx < Nn) {
      rowp[idx] = run;
      run += counts[idx];
    }
  }
  if (t == 1023) rowp[Nn] = part[1023];
}

__global__ __launch_bounds__(256) void fill_k(const int* __restrict__ dst,
                                              const int* __restrict__ rowp,
                                              int* __restrict__ cursor,
                                              int* __restrict__ eidx, int E_) {
  int e = blockIdx.x * 256 + threadIdx.x;
  if (e >= E_) return;
  int d = dst[e];
  int pos = atomicAdd(&cursor[d], 1);
  eidx[rowp[d] + pos] = e;
}

// Precompute dst-sorted streams (graph + masks fixed across all 6 EGAT passes):
// srcS[i]=src[eidx[i]], maskS/mask2S likewise, pos[e]=CSR position of edge e.

__global__ __launch_bounds__(256) void sortstreams_k(
    const int* __restrict__ eidx, const int* __restrict__ src,
    const float* __restrict__ mask, const float* __restrict__ mask2,
    int* __restrict__ srcS, float* __restrict__ maskS, float* __restrict__ mask2S,
    int* __restrict__ pos, int E_) {
  int i = blockIdx.x * 256 + threadIdx.x;
  if (i >= E_) return;
  int e = eidx[i];
  srcS[i] = src[e];
  maskS[i] = mask[e];
  mask2S[i] = mask2[e];
  pos[e] = i;
}

// ---------------- weight fold: Wq[k, h*64+j] = sum_d Wn[k,h*64+d]*aggW[h*64+d,j] ----

__global__ __launch_bounds__(256) void wq_k(const float* __restrict__ Wn,
                                            const float* __restrict__ aggW,
                                            float* __restrict__ Wq) {
  __shared__ float A[64][65];   // A[k][d]
  __shared__ float Bm[64][65];  // B[d][j]
  int h = blockIdx.x;
  int t = threadIdx.x;
  for (int idx = t; idx < 4096; idx += 256) {
    int k = idx >> 6, d = idx & 63;
    A[k][d] = Wn[k * 256 + h * 64 + d];
  }
  for (int idx = t; idx < 4096; idx += 256) {
    int d = idx >> 6, j = idx & 63;
    Bm[d][j] = aggW[(h * 64 + d) * 64 + j];
  }
  __syncthreads();
  int j = t & 63, rg = t >> 6;
#pragma unroll
  for (int i = 0; i < 16; i++) {
    int k = rg * 16 + i;
    float acc = 0.f;
#pragma unroll 16
    for (int d = 0; d < 64; d++) acc += A[k][d] * Bm[d][j];
    Wq[k * 256 + h * 64 + j] = acc;
  }
}

// ---------------- fused projection: P[N,384] = A @ [Wq | Wni | Wnj] ----------------

__global__ __launch_bounds__(256) void proj_k(const float* __restrict__ A,
                                              const float* __restrict__ Wq,
                                              const float* __restrict__ Wni,
                                              const float* __restrict__ Wnj,
                                              float* __restrict__ P, int M) {
  __shared__ float As[64][65];
  __shared__ float Bs[64][65];
  int row0 = blockIdx.x * 64;
  int c = threadIdx.x & 63;
  int rg = threadIdx.x >> 6;
#pragma unroll
  for (int i = 0; i < 16; i++) {
    int idx = threadIdx.x + i * 256;
    int r = idx >> 6, kk = idx & 63;
    As[r][kk] = (row0 + r < M) ? A[(size_t)(row0 + r) * 64 + kk] : 0.f;
  }
  for (int cb = 0; cb < 6; cb++) {
    const float* B = cb < 4 ? Wq : (cb == 4 ? Wni : Wnj);
    int bcol = cb < 4 ? cb * 64 : 0;
    int bld = cb < 4 ? 256 : 64;
    __syncthreads();
#pragma unroll
    for (int i = 0; i < 16; i++) {
      int idx = threadIdx.x + i * 256;
      int kk = idx >> 6, cc = idx & 63;
      Bs[kk][cc] = B[(size_t)kk * bld + bcol + cc];
    }
    __syncthreads();
    float acc[16];
#pragma unroll
    for (int i = 0; i < 16; i++) acc[i] = 0.f;
#pragma unroll 16
    for (int kk = 0; kk < 64; kk++) {
      float bv = Bs[kk][c];
#pragma unroll
      for (int i = 0; i < 16; i++) acc[i] += As[rg * 16 + i][kk] * bv;
    }
#pragma unroll
    for (int i = 0; i < 16; i++) {
      int r = row0 + rg * 16 + i;
      if (r < M) P[(size_t)r * 384 + cb * 64 + c] = acc[i];
    }
  }
}

// ---------------- edge kernel: attention logits -> exp (CSR-ordered output) --------
// One wave per edge; lane c owns column c of H*FE=64. Wf column in 64 VGPRs
// (launch_bounds(256,4) -> 128-VGPR cap keeps it resident). EF row loaded
// COALESCED (lane c -> EF[e*K+c]) then broadcast in-register via v_readlane:
// inner loop is {v_readlane, v_fmac} x K, zero LDS, zero scalar-mem.

__device__ __forceinline__ float bcast_lane(float v, int lane) {
  return __uint_as_float(__builtin_amdgcn_readlane(__float_as_uint(v), lane));
}

template <int K>
__global__ __launch_bounds__(256, 4) void edge_k(const float* __restrict__ P,
                                                 const float* __restrict__ EF,
                                                 const float* __restrict__ Wf,
                                                 const float* __restrict__ attn,
                                                 const float* __restrict__ bias,
                                                 const int* __restrict__ src,
                                                 const int* __restrict__ dst,
                                                 const int* __restrict__ pos,
                                                 float* __restrict__ EXS, int E_) {
  int c = threadIdx.x & 63;
  int le = threadIdx.x >> 6;
  float wreg[K];
#pragma unroll
  for (int k = 0; k < K; k++) wreg[k] = Wf[k * 64 + c];
  float att = attn[c];
  float bi = bias[c];
  int ngroups = (E_ + 3) >> 2;
  for (int g = blockIdx.x; g < ngroups; g += gridDim.x) {
    int e = g * 4 + le;
    if (e >= E_) continue;
    int s = src[e], d = dst[e], pe = pos[e];
    float efv = (c < K) ? EF[(size_t)e * K + c] : 0.f;
    float f0 = P[(size_t)s * 384 + 256 + c] + P[(size_t)d * 384 + 320 + c] + bi;
    float f1 = 0.f, f2 = 0.f, f3 = 0.f;
#pragma unroll
    for (int k = 0; k < K; k += 4) {
      f0 += bcast_lane(efv, k) * wreg[k];
      f1 += bcast_lane(efv, k + 1) * wreg[k + 1];
      f2 += bcast_lane(efv, k + 2) * wreg[k + 2];
      f3 += bcast_lane(efv, k + 3) * wreg[k + 3];
    }
    float f = (f0 + f1) + (f2 + f3);
    f = f > 0.f ? f : 0.01f * f;
    float v = f * att;
    v += __shfl_xor(v, 1);
    v += __shfl_xor(v, 2);
    v += __shfl_xor(v, 4);
    v += __shfl_xor(v, 8);
    if ((c & 15) == 0) EXS[(size_t)pe * 4 + (c >> 4)] = __expf(v);
  }
}

// ---------------- per-destination aggregation + folded agg-GEMM epilogue -----------
// ONE WAVE PER NODE. Lane t owns cols 4t..4t+3 (head h = t>>4) of Q = x@Wq.
// Streams srcS/maskS/EXS are contiguous in CSR order. Per-head normalize, then
// cross-head sum via shfl_xor(16/32); lanes 0..15 write act(sum_h + bias) as float4.
// ACT: 1 = ELU, 2 = leaky_relu(0.01)

template <int ACT>
__global__ __launch_bounds__(256) void node_agg_k(const float* __restrict__ P,
                                                  const float* __restrict__ EXS,
                                                  const float* __restrict__ maskS,
                                                  const int* __restrict__ srcS,
                                                  const int* __restrict__ rowp,
                                                  const float* __restrict__ bias,
                                                  float* __restrict__ Xout, int Nn) {
  int wid = (blockIdx.x * 256 + threadIdx.x) >> 6;
  if (wid >= Nn) return;
  int t = threadIdx.x & 63;
  int h = t >> 4;
  int beg = rowp[wid], end = rowp[wid + 1];
  float ax = 0.f, ay = 0.f, az = 0.f, aw = 0.f, ssum = 0.f;
  if (beg < end) {
    int s = srcS[beg];
    float ex = EXS[(size_t)beg * 4 + h];
    float mk = maskS[beg];
    float4 pv = *(const float4*)(P + (size_t)s * 384 + t * 4);
    for (int i = beg + 1; i < end; i++) {
      int s2 = srcS[i];
      float ex2 = EXS[(size_t)i * 4 + h];
      float mk2 = maskS[i];
      float4 pv2 = *(const float4*)(P + (size_t)s2 * 384 + t * 4);
      float w = ex * mk;
      ax += w * pv.x; ay += w * pv.y; az += w * pv.z; aw += w * pv.w;
      ssum += ex;
      s = s2; ex = ex2; mk = mk2; pv = pv2;
    }
    float w = ex * mk;
    ax += w * pv.x; ay += w * pv.y; az += w * pv.z; aw += w * pv.w;
    ssum += ex;
  }
  float inv = (ssum > 0.f) ? 1.f / ssum : 0.f;
  ax *= inv; ay *= inv; az *= inv; aw *= inv;
  // sum over heads: lanes t, t^16, t^32, t^48 hold the same j-quad
  ax += __shfl_xor(ax, 16); ay += __shfl_xor(ay, 16);
  az += __shfl_xor(az, 16); aw += __shfl_xor(aw, 16);
  ax += __shfl_xor(ax, 32); ay += __shfl_xor(ay, 32);
  az += __shfl_xor(az, 32); aw += __shfl_xor(aw, 32);
  if (t < 16) {
    float4 b = *(const float4*)(bias + t * 4);
    float vx = ax + b.x, vy = ay + b.y, vz = az + b.z, vw = aw + b.w;
    if (ACT == 1) {
      vx = vx > 0.f ? vx : expm1f(vx);
      vy = vy > 0.f ? vy : expm1f(vy);
      vz = vz > 0.f ? vz : expm1f(vz);
      vw = vw > 0.f ? vw : expm1f(vw);
    } else {
      vx = vx > 0.f ? vx : 0.01f * vx;
      vy = vy > 0.f ? vy : 0.01f * vy;
      vz = vz > 0.f ? vz : 0.01f * vz;
      vw = vw > 0.f ? vw : 0.01f * vw;
    }
    *(float4*)(Xout + (size_t)wid * 64 + t * 4) = make_float4(vx, vy, vz, vw);
  }
}

// ---------------- gathers into head feature matrices ----------------

__global__ __launch_bounds__(64) void gather2_k(const float* __restrict__ X,
                                                const int* __restrict__ uidx,
                                                const int* __restrict__ iidx,
                                                float* __restrict__ uiX, int layer) {
  int b = blockIdx.x;
  int c = threadIdx.x;
  uiX[(size_t)b * 384 + layer * 64 + c] = X[(size_t)uidx[b] * 64 + c];
  uiX[(size_t)b * 384 + 192 + layer * 64 + c] = X[(size_t)iidx[b] * 64 + c];
}

__global__ __launch_bounds__(64) void gather1_k(const float* __restrict__ X,
                                                const int* __restrict__ sidx,
                                                float* __restrict__ sgX, int layer) {
  int b = blockIdx.x;
  int c = threadIdx.x;
  sgX[(size_t)b * 192 + layer * 64 + c] = X[(size_t)sidx[b] * 64 + c];
}

// ---------------- head MLP: sigmoid(relu(X@W1+b1)@W2+b2) ----------------

__global__ __launch_bounds__(128) void head_k(const float* __restrict__ Xf,
                                              const float* __restrict__ W1,
                                              const float* __restrict__ b1,
                                              const float* __restrict__ W2,
                                              const float* __restrict__ b2,
                                              float* __restrict__ out, int F) {
  __shared__ float xs[384];
  __shared__ float red[128];
  int b = blockIdx.x, t = threadIdx.x;
  for (int i = t; i < F; i += 128) xs[i] = Xf[(size_t)b * F + i];
  __syncthreads();
  float acc = b1[t];
  for (int k = 0; k < F; k++) acc += xs[k] * W1[k * 128 + t];
  acc = fmaxf(acc, 0.f);
  float v = acc * W2[t];
  v += __shfl_xor(v, 1);
  v += __shfl_xor(v, 2);
  v += __shfl_xor(v, 4);
  v += __shfl_xor(v, 8);
  v += __shfl_xor(v, 16);
  v += __shfl_xor(v, 32);
  red[t] = v;
  __syncthreads();
  if (t == 0) {
    float tot = red[0] + red[64] + b2[0];
    out[b] = 1.f / (1.f + __expf(-tot));
  }
}

// ---------------- driver ----------------

extern "C" void kernel_launch(void* const* d_in, const int* in_sizes, int n_in,
                              void* d_out, int out_size, void* d_ws, size_t ws_size,
                              hipStream_t stream) {
  const float* x_in = (const float*)d_in[0];
  const float* efeat = (const float*)d_in[1];
  const float* efeat2 = (const float*)d_in[2];
  const float* mask = (const float*)d_in[3];
  const float* mask2 = (const float*)d_in[4];
  const int* src = (const int*)d_in[5];
  const int* dst = (const int*)d_in[6];
  const int* user_idx = (const int*)d_in[7];
  const int* item_idx = (const int*)d_in[8];
  const int* subg_idx = (const int*)d_in[9];
  const float* lW_node = (const float*)d_in[10];
  const float* lW_ni = (const float*)d_in[11];
  const float* lW_nj = (const float*)d_in[12];
  const float* lW_fij = (const float*)d_in[13];
  const float* l_attn = (const float*)d_in[14];
  const float* l_bias = (const float*)d_in[15];
  const float* agg1_W = (const float*)d_in[16];
  const float* agg1_b = (const float*)d_in[17];
  const float* gW_node = (const float*)d_in[18];
  const float* gW_ni = (const float*)d_in[19];
  const float* gW_nj = (const float*)d_in[20];
  const float* gW_fij = (const float*)d_in[21];
  const float* g_attn = (const float*)d_in[22];
  const float* g_bias = (const float*)d_in[23];
  const float* agg2_W = (const float*)d_in[24];
  const float* agg2_b = (const float*)d_in[25];
  const float* lin1_ui_W = (const float*)d_in[26];
  const float* lin1_ui_b = (const float*)d_in[27];
  const float* lin2_ui_W = (const float*)d_in[28];
  const float* lin2_ui_b = (const float*)d_in[29];
  const float* lin1_sg_W = (const float*)d_in[30];
  const float* lin1_sg_b = (const float*)d_in[31];
  const float* lin2_sg_W = (const float*)d_in[32];
  const float* lin2_sg_b = (const float*)d_in[33];

  float* out = (float*)d_out;

  // workspace layout (floats)
  float* ws = (float*)d_ws;
  float* P = ws;                          // [N,384]: Q | NI | NJ
  float* Xc = P + (size_t)NN * 384;       // [N,64]
  float* EXS = Xc + (size_t)NN * 64;      // [E,4] CSR-ordered
  float* Wq = EXS + (size_t)EE * 4;       // [64,256]
  float* uiX = Wq + 64 * 256;             // [B,384]
  float* sgX = uiX + (size_t)BB * 384;    // [B,192]
  float* maskS = sgX + (size_t)BB * 192;  // [E]
  float* mask2S = maskS + EE;             // [E]
  int* rowp = (int*)(mask2S + EE);        // [N+1]
  int* counts = rowp + (NN + 1);          // [N]
  int* eidx = counts + NN;                // [E]
  int* srcS = eidx + EE;                  // [E]
  int* pos = srcS + EE;                   // [E]

  // ---- CSR by dst + sorted streams (shared by all 6 EGAT passes) ----
  hipMemsetAsync(counts, 0, NN * sizeof(int), stream);
  count_k<<<(EE + 255) / 256, 256, 0, stream>>>(dst, counts, EE);
  scan_k<<<1, 1024, 0, stream>>>(counts, rowp, NN);
  hipMemsetAsync(counts, 0, NN * sizeof(int), stream);
  fill_k<<<(EE + 255) / 256, 256, 0, stream>>>(dst, rowp, counts, eidx, EE);
  sortstreams_k<<<(EE + 255) / 256, 256, 0, stream>>>(eidx, src, mask, mask2, srcS,
                                                      maskS, mask2S, pos, EE);

  // x working copy
  hipMemcpyAsync(Xc, x_in, (size_t)NN * 64 * sizeof(float), hipMemcpyDeviceToDevice,
                 stream);

  int gProj = (NN + 63) / 64;
  int edgeBlocks = 2048;
  int gAggN = (NN * 64 + 255) / 256;  // one wave per node

  for (int i = 0; i < LL; i++) {
    // ===== local EGAT =====
    wq_k<<<4, 256, 0, stream>>>(lW_node + (size_t)i * 64 * 256,
                                agg1_W + (size_t)i * 256 * 64, Wq);
    proj_k<<<gProj, 256, 0, stream>>>(Xc, Wq, lW_ni + (size_t)i * 64 * 64,
                                      lW_nj + (size_t)i * 64 * 64, P, NN);
    edge_k<8><<<edgeBlocks, 256, 0, stream>>>(P, efeat, lW_fij + (size_t)i * 8 * 64,
                                              l_attn + (size_t)i * 64,
                                              l_bias + (size_t)i * 64, src, dst, pos,
                                              EXS, EE);
    node_agg_k<1><<<gAggN, 256, 0, stream>>>(P, EXS, maskS, srcS, rowp,
                                             agg1_b + (size_t)i * 64, Xc, NN);
    gather2_k<<<BB, 64, 0, stream>>>(Xc, user_idx, item_idx, uiX, i);

    // ===== global EGAT =====
    wq_k<<<4, 256, 0, stream>>>(gW_node + (size_t)i * 64 * 256,
                                agg2_W + (size_t)i * 256 * 64, Wq);
    proj_k<<<gProj, 256, 0, stream>>>(Xc, Wq, gW_ni + (size_t)i * 64 * 64,
                                      gW_nj + (size_t)i * 64 * 64, P, NN);
    edge_k<64><<<edgeBlocks, 256, 0, stream>>>(
        P, efeat2, gW_fij + (size_t)i * 64 * 64, g_attn + (size_t)i * 64,
        g_bias + (size_t)i * 64, src, dst, pos, EXS, EE);
    node_agg_k<2><<<gAggN, 256, 0, stream>>>(P, EXS, mask2S, srcS, rowp,
                                             agg2_b + (size_t)i * 64, Xc, NN);
    gather1_k<<<BB, 64, 0, stream>>>(Xc, subg_idx, sgX, i);
  }

  // ===== heads =====  output order: (subg_o, ui_o)
  head_k<<<BB, 128, 0, stream>>>(sgX, lin1_sg_W, lin1_sg_b, lin2_sg_W, lin2_sg_b, out,
                                 192);
  head_k<<<BB, 128, 0, stream>>>(uiX, lin1_ui_W, lin1_ui_b, lin2_ui_W, lin2_ui_b,
                                 out + BB, 384);
}